// Round 2
// 163.801 us; speedup vs baseline: 1.1315x; 1.1315x over previous
//
#include <hip/hip_runtime.h>
#include <math.h>

#define U 128
#define GAMMA 28
#define TB 16        // batch rows per block (one MFMA tile N-dim)
#define NT 512       // 8 waves
#define HSTR 136     // halves per hA row: 128 + 8 pad (272 B, 16B-aligned)
#define ESTR 260     // floats per wfin row: 258 -> 260 (1040 B, 16B-aligned)
#define L2E 1.4426950408889634f

typedef _Float16 half8 __attribute__((ext_vector_type(8)));
typedef _Float16 half4 __attribute__((ext_vector_type(4)));
typedef float floatx4 __attribute__((ext_vector_type(4)));

// raw v_exp_f32 (exp2) through the compiler intrinsic so the TRANS-result
// hazard gets its required wait state (inline asm hid it -> NaN in R1).
__device__ __forceinline__ float exp2_f(float x) {
#if __has_builtin(__builtin_amdgcn_exp2f)
    return __builtin_amdgcn_exp2f(x);
#else
    return exp2f(x);
#endif
}
__device__ __forceinline__ float rcp_f(float x) { return __builtin_amdgcn_rcpf(x); }
__device__ __forceinline__ float softplus_f(float x) {
    return fmaxf(x, 0.0f) + __logf(1.0f + __expf(-fabsf(x)));
}

__global__ __launch_bounds__(NT, 4) void fib_rnn_kernel(
    const float* __restrict__ inp,      // (B,49,1)
    const float* __restrict__ Kw,       // (1,384)
    const float* __restrict__ Rw,       // (128,384)
    const float* __restrict__ bias,     // (2,384)
    const float* __restrict__ dv_loc,   // (258)
    const float* __restrict__ dv_rho,   // (258)
    const float* __restrict__ dv_eps,   // (28,258)
    const float* __restrict__ samp,     // (27,B,1)
    float* __restrict__ out,            // (B,28,2)
    int B)
{
    __shared__ __align__(16) _Float16 hA[2][TB * HSTR];
    __shared__ __align__(16) float wfin[GAMMA * ESTR];   // per-step dense weights [s][2j+n]
    __shared__ float in_lds[TB * 49];
    __shared__ float samp_lds[27 * TB];
    __shared__ __align__(16) float wsum[2][8][TB][2];    // [parity][wave][row][n]
    __shared__ float epsB[GAMMA][2];
    __shared__ __align__(16) float out_lds[TB * GAMMA * 2]; // staged output (coalesced store at end)

    const int tid  = threadIdx.x;
    const int wv   = tid >> 6;          // wave 0..7
    const int lane = tid & 63;
    const int q    = lane >> 4;         // quad 0..3
    const int m16  = lane & 15;         // this lane's batch row
    const int j0   = wv * 16 + q * 4;   // first of this lane's 4 gate columns
    const int b0   = blockIdx.x * TB;

    const float Cc = 0.5413248546f;     // log(expm1(1))

    // ---- one-time staging
    for (int i = tid; i < TB * 48; i += NT) {
        int bl = i / 48, tt = i - bl * 48;
        in_lds[bl * 49 + tt] = inp[(size_t)(b0 + bl) * 49 + tt];
    }
    for (int i = tid; i < 2 * TB * HSTR; i += NT) (&hA[0][0])[i] = (_Float16)0.f;
    for (int i = tid; i < GAMMA * 258; i += NT) {
        int s = i / 258, t = i - 258 * s;
        float v = dv_eps[i];
        if (t < 256) {
            float sc = 1e-5f + 0.02f * softplus_f(Cc + dv_rho[t]);
            wfin[s * ESTR + t] = fmaf(sc, v, dv_loc[t]);
        } else {
            epsB[s][t - 256] = v;
        }
    }
    for (int i = tid; i < 27 * TB; i += NT) {
        int s = i >> 4, bl = i & 15;
        samp_lds[i] = samp[(size_t)s * B + b0 + bl];
    }

    // ---- stationary R^T fragments (A operand, fp16), PRE-SCALED:
    // z,r tiles by -log2e; hh tile by -2log2e — so gates use raw exp2.
    half8 Rb[3][4];
    {
        const int   tiles[3] = {wv, wv + 8, wv + 16};
        const float tsc[3]   = {-L2E, -L2E, -2.0f * L2E};
        #pragma unroll
        for (int t = 0; t < 3; ++t) {
            const int c = tiles[t] * 16 + m16;
            #pragma unroll
            for (int kt = 0; kt < 4; ++kt) {
                #pragma unroll
                for (int e = 0; e < 8; ++e)
                    Rb[t][kt][e] = (_Float16)(tsc[t] * Rw[(size_t)(kt * 32 + q * 8 + e) * 384 + c]);
            }
        }
    }

    // per-lane gate constants for columns j0..j0+3 (same scaling as Rb)
    float KzS[4], KrS[4], KhS[4], bzS[4], brS[4], bhxS[4], bhhS[4];
    #pragma unroll
    for (int i = 0; i < 4; ++i) {
        const int j = j0 + i;
        KzS[i]  = -L2E * Kw[j];
        KrS[i]  = -L2E * Kw[j + U];
        KhS[i]  = -2.0f * L2E * Kw[j + 2 * U];
        bzS[i]  = -L2E * (bias[j] + bias[384 + j]);
        brS[i]  = -L2E * (bias[j + U] + bias[384 + j + U]);
        bhxS[i] = -2.0f * L2E * bias[j + 2 * U];        // outside r-mult
        bhhS[i] = -2.0f * L2E * bias[384 + j + 2 * U];  // inside  r-mult -> acc2 init
    }
    const float wbl0 = dv_loc[256], wbl1 = dv_loc[257];
    const float wbs0 = 1e-5f + 0.02f * softplus_f(Cc + dv_rho[256]);
    const float wbs1 = 1e-5f + 0.02f * softplus_f(Cc + dv_rho[257]);

    float hprev[4] = {0.f, 0.f, 0.f, 0.f};

    __syncthreads();

    // ---- helpers
    auto mfma3 = [&](const int cu, floatx4& a0, floatx4& a1, floatx4& a2) {
        #pragma unroll
        for (int kt = 0; kt < 4; ++kt) {
            const half8 Bh = *reinterpret_cast<const half8*>(&hA[cu][m16 * HSTR + kt * 32 + q * 8]);
            a0 = __builtin_amdgcn_mfma_f32_16x16x32_f16(Rb[0][kt], Bh, a0, 0, 0, 0);
            a1 = __builtin_amdgcn_mfma_f32_16x16x32_f16(Rb[1][kt], Bh, a1, 0, 0, 0);
            a2 = __builtin_amdgcn_mfma_f32_16x16x32_f16(Rb[2][kt], Bh, a2, 0, 0, 0);
        }
    };
    auto hstore = [&](const int cu, const float hn[4]) {
        half4 hp;
        #pragma unroll
        for (int i = 0; i < 4; ++i) hp[i] = (_Float16)hn[i];
        *reinterpret_cast<half4*>(&hA[cu ^ 1][m16 * HSTR + j0]) = hp;
    };
    auto dense_part = [&](const int s, const float hn[4]) {
        const float4 wa = *reinterpret_cast<const float4*>(&wfin[s * ESTR + 2 * j0]);
        const float4 wb = *reinterpret_cast<const float4*>(&wfin[s * ESTR + 2 * j0 + 4]);
        float pv0 = hn[0] * wa.x + hn[1] * wa.z + hn[2] * wb.x + hn[3] * wb.z;
        float pv1 = hn[0] * wa.y + hn[1] * wa.w + hn[2] * wb.y + hn[3] * wb.w;
        pv0 += __shfl_xor(pv0, 16, 64);  pv1 += __shfl_xor(pv1, 16, 64);
        pv0 += __shfl_xor(pv0, 32, 64);  pv1 += __shfl_xor(pv1, 32, 64);
        if (q == 0)
            *reinterpret_cast<float2*>(&wsum[s & 1][wv][m16][0]) = make_float2(pv0, pv1);
    };

    // ================= encoder steps 0..46 (x known ahead -> fold x@K + bias
    // into the MFMA C-init: 8 fma + 4 mov replace 12 zero-movs for free) ====
    float xcur = in_lds[m16 * 49];
    #pragma unroll 2
    for (int step = 0; step < 47; ++step) {
        const int cu = step & 1;                         // constant-folds under unroll 2
        const float xnext = in_lds[m16 * 49 + step + 1]; // prefetch; latency hidden by gates
        floatx4 a0, a1, a2;
        #pragma unroll
        for (int i = 0; i < 4; ++i) {
            a0[i] = fmaf(xcur, KzS[i], bzS[i]);
            a1[i] = fmaf(xcur, KrS[i], brS[i]);
            a2[i] = bhhS[i];
        }
        mfma3(cu, a0, a1, a2);
        float hn[4];
        #pragma unroll
        for (int i = 0; i < 4; ++i) {
            const float z  = rcp_f(1.0f + exp2_f(a0[i]));
            const float r  = rcp_f(1.0f + exp2_f(a1[i]));
            const float t  = fmaf(r, a2[i], fmaf(xcur, KhS[i], bhxS[i]));
            const float hh = fmaf(2.0f, rcp_f(1.0f + exp2_f(t)), -1.0f);
            hn[i] = fmaf(z, hprev[i] - hh, hh);
            hprev[i] = hn[i];
        }
        hstore(cu, hn);
        xcur = xnext;
        __syncthreads();
    }

    // ================= step 47 (last encoder step; emits dense partials s=0)
    {
        floatx4 a0, a1, a2;
        #pragma unroll
        for (int i = 0; i < 4; ++i) {
            a0[i] = fmaf(xcur, KzS[i], bzS[i]);
            a1[i] = fmaf(xcur, KrS[i], brS[i]);
            a2[i] = bhhS[i];
        }
        mfma3(1, a0, a1, a2);
        float hn[4];
        #pragma unroll
        for (int i = 0; i < 4; ++i) {
            const float z  = rcp_f(1.0f + exp2_f(a0[i]));
            const float r  = rcp_f(1.0f + exp2_f(a1[i]));
            const float t  = fmaf(r, a2[i], fmaf(xcur, KhS[i], bhxS[i]));
            const float hh = fmaf(2.0f, rcp_f(1.0f + exp2_f(t)), -1.0f);
            hn[i] = fmaf(z, hprev[i] - hh, hh);
            hprev[i] = hn[i];
        }
        hstore(1, hn);
        dense_part(0, hn);
        __syncthreads();
    }

    // ================= feedback steps 48..74 (y from phase A; biases in C-init,
    // x*K stays as one fma per gate so phase A overlaps the MFMA chain) ======
    #pragma unroll 2
    for (int step = 48; step < 75; ++step) {
        const int cu = step & 1;
        const int sp = step - 48;
        floatx4 a0, a1, a2;
        #pragma unroll
        for (int i = 0; i < 4; ++i) { a0[i] = bzS[i]; a1[i] = brS[i]; a2[i] = bhhS[i]; }
        mfma3(cu, a0, a1, a2);

        // phase A: finish previous step's dense_var; produce this lane's y
        float sx = 0.f, sy = 0.f;
        #pragma unroll
        for (int w = 0; w < 8; ++w) {
            const float2 f = *reinterpret_cast<const float2*>(&wsum[sp & 1][w][m16][0]);
            sx += f.x; sy += f.y;
        }
        const float x20 = sx + fmaf(wbs0, epsB[sp][0], wbl0);
        const float x21 = sy + fmaf(wbs1, epsB[sp][1], wbl1);
        const float sc  = 1e-5f + 0.05f * softplus_f(Cc + x21);
        if (wv == 0 && q == 0)
            *reinterpret_cast<float2*>(&out_lds[m16 * 56 + sp * 2]) = make_float2(x20, sc);
        const float yv = fmaf(sc, samp_lds[sp * 16 + m16], x20);

        float hn[4];
        #pragma unroll
        for (int i = 0; i < 4; ++i) {
            const float z  = rcp_f(1.0f + exp2_f(fmaf(yv, KzS[i], a0[i])));
            const float r  = rcp_f(1.0f + exp2_f(fmaf(yv, KrS[i], a1[i])));
            const float t  = fmaf(r, a2[i], fmaf(yv, KhS[i], bhxS[i]));
            const float hh = fmaf(2.0f, rcp_f(1.0f + exp2_f(t)), -1.0f);
            hn[i] = fmaf(z, hprev[i] - hh, hh);
            hprev[i] = hn[i];
        }
        hstore(cu, hn);
        dense_part(step - 47, hn);
        __syncthreads();
    }

    // ---- final output s = 27 (parity 1)
    if (wv == 0 && q == 0) {
        float sx = 0.f, sy = 0.f;
        #pragma unroll
        for (int w = 0; w < 8; ++w) {
            const float2 f = *reinterpret_cast<const float2*>(&wsum[1][w][m16][0]);
            sx += f.x; sy += f.y;
        }
        const float x20 = sx + fmaf(wbs0, epsB[27][0], wbl0);
        const float x21 = sy + fmaf(wbs1, epsB[27][1], wbl1);
        const float sc  = 1e-5f + 0.05f * softplus_f(Cc + x21);
        *reinterpret_cast<float2*>(&out_lds[m16 * 56 + 54]) = make_float2(x20, sc);
    }
    __syncthreads();

    // ---- coalesced output burst: 16 rows x 28 x 2 floats = 224 float4, contiguous
    if (tid < 224) {
        const float4 v = reinterpret_cast<const float4*>(out_lds)[tid];
        reinterpret_cast<float4*>(out + (size_t)b0 * 56)[tid] = v;
    }
}

extern "C" void kernel_launch(void* const* d_in, const int* in_sizes, int n_in,
                              void* d_out, int out_size, void* d_ws, size_t ws_size,
                              hipStream_t stream) {
    const float* inp    = (const float*)d_in[0];
    const float* Kw     = (const float*)d_in[1];
    const float* Rw     = (const float*)d_in[2];
    const float* bias   = (const float*)d_in[3];
    const float* dv_loc = (const float*)d_in[4];
    const float* dv_rho = (const float*)d_in[5];
    const float* dv_eps = (const float*)d_in[6];
    const float* samp   = (const float*)d_in[7];
    float* out = (float*)d_out;
    const int B = in_sizes[0] / 49;   // 8192
    dim3 grid(B / TB), block(NT);
    hipLaunchKernelGGL(fib_rnn_kernel, grid, block, 0, stream,
                       inp, Kw, Rw, bias, dv_loc, dv_rho, dv_eps, samp, out, B);
}